// Round 17
// baseline (79.626 us; speedup 1.0000x reference)
//
#include <hip/hip_runtime.h>

#define IW 512
#define IH 512
#define NPIX (IH * IW)
#define NK 6            // steps 1..6 (step 0 is exact identity)
#define GROUPS 8        // group == bid&7 == XCD -> 3 planes per XCD, L2-resident
#define PPT 3

typedef float f2v __attribute__((ext_vector_type(2), aligned(4)));

__global__ __launch_bounds__(256, 6) void zoomblur_kernel(
    const float* __restrict__ img,
    const float* __restrict__ zoomf,
    float* __restrict__ out)
{
    const int tid   = threadIdx.x;
    const int bid   = blockIdx.x;
    const int group = bid & (GROUPS - 1);   // == XCD (round-robin dispatch)
    const int y     = bid >> 3;             // one output row per block

    const float zf = 0.85f + 0.30f * zoomf[0];
    const float dz = zf - 1.0f;
    const float yf  = (float)y - 256.0f;
    const float xfA = (float)tid - 256.0f;  // pixel A: x = tid
    const float xfB = (float)tid;           // pixel B: x = tid + 256

    // ---- per-(step,pixel) precompute: offsets, lerp weights, t-weights ----
    int   offA[NK], offB[NK];
    float wxA[NK], wxB[NK];
    float t0A[NK], t1A[NK], t0B[NK], t1B[NK];
    int mAm1 = 0, mAp5 = 0, mBm1 = 0, mBp5 = 0;   // exact-boundary flags

#pragma unroll
    for (int k = 0; k < NK; ++k) {
        const float inv = __builtin_amdgcn_rcpf(
            fmaf((float)(k + 1) * (1.0f / 6.0f), dz, 1.0f));
        // vertical (shared geometry; t carries the 1/7 and the OOB zeroing)
        const float ys = fmaf(yf, inv, 256.0f);
        const float fy = floorf(ys);
        const float wy = ys - fy;
        const int y0 = (int)fy;
        const int yb = min(max(y0, 0), IH - 2);
        const float ta = ((yb == y0 ? 1.0f - wy : 0.0f) +
                          (yb == y0 + 1 ? wy : 0.0f)) * (1.0f / 7.0f);
        const float tb = ((yb + 1 == y0 ? 1.0f - wy : 0.0f) +
                          (yb + 1 == y0 + 1 ? wy : 0.0f)) * (1.0f / 7.0f);
        // horizontal A
        const float xsA = fmaf(xfA, inv, 256.0f);
        const float fxA = floorf(xsA);
        wxA[k] = xsA - fxA;
        const int x0A = (int)fxA;
        const int xbA = min(max(x0A, 0), IW - 2);
        const bool xokA = (x0A >= -1) & (x0A <= IW - 1);
        t0A[k] = xokA ? ta : 0.0f;
        t1A[k] = xokA ? tb : 0.0f;
        mAm1 |= (x0A == -1)     << k;
        mAp5 |= (x0A == IW - 1) << k;
        offA[k] = yb * IW + xbA;
        // horizontal B
        const float xsB = fmaf(xfB, inv, 256.0f);
        const float fxB = floorf(xsB);
        wxB[k] = xsB - fxB;
        const int x0B = (int)fxB;
        const int xbB = min(max(x0B, 0), IW - 2);
        const bool xokB = (x0B >= -1) & (x0B <= IW - 1);
        t0B[k] = xokB ? ta : 0.0f;
        t1B[k] = xokB ? tb : 0.0f;
        mBm1 |= (x0B == -1)     << k;
        mBp5 |= (x0B == IW - 1) << k;
        offB[k] = yb * IW + xbB;
    }

    // wave-uniform: does this wave contain any exact-boundary lane?
    const bool edgeWave = __any((mAm1 | mAp5 | mBm1 | mBp5) != 0);

    const int idoff = y * IW + tid;
    const size_t pbase = (size_t)(group * PPT) * NPIX;
    const float* __restrict__ ib = img + pbase;
    float* __restrict__       ob = out + pbase;

    // ---- gather loop: no LDS, no barriers; waves fully independent ----
#pragma unroll
    for (int p = 0; p < PPT; ++p) {
        const float* __restrict__ base = ib + (size_t)p * NPIX;
        float accA = base[idoff]       * (1.0f / 7.0f);   // step 0: identity
        float accB = base[idoff + 256] * (1.0f / 7.0f);
#pragma unroll
        for (int k = 0; k < NK; ++k) {
            // 4 b64 tap-pair loads; row+1 folds to a +2048B inst offset
            const f2v a0 = *(const f2v*)(base + offA[k]);
            const f2v a1 = *(const f2v*)(base + offA[k] + IW);
            const f2v b0 = *(const f2v*)(base + offB[k]);
            const f2v b1 = *(const f2v*)(base + offB[k] + IW);
            float rA0 = fmaf(wxA[k], a0.y - a0.x, a0.x);
            float rA1 = fmaf(wxA[k], a1.y - a1.x, a1.x);
            float rB0 = fmaf(wxB[k], b0.y - b0.x, b0.x);
            float rB1 = fmaf(wxB[k], b1.y - b1.x, b1.x);
            if (edgeWave) {   // wave-uniform branch: only edge waves pay
                const bool am1 = (mAm1 >> k) & 1, ap5 = (mAp5 >> k) & 1;
                const bool bm1 = (mBm1 >> k) & 1, bp5 = (mBp5 >> k) & 1;
                // x0==-1: taps (0, col0); x0==511: taps (col511, 0)
                float v0, v1;
                v0 = am1 ? 0.0f : (ap5 ? a0.y : a0.x);
                v1 = am1 ? a0.x : (ap5 ? 0.0f : a0.y);
                rA0 = fmaf(wxA[k], v1 - v0, v0);
                v0 = am1 ? 0.0f : (ap5 ? a1.y : a1.x);
                v1 = am1 ? a1.x : (ap5 ? 0.0f : a1.y);
                rA1 = fmaf(wxA[k], v1 - v0, v0);
                v0 = bm1 ? 0.0f : (bp5 ? b0.y : b0.x);
                v1 = bm1 ? b0.x : (bp5 ? 0.0f : b0.y);
                rB0 = fmaf(wxB[k], v1 - v0, v0);
                v0 = bm1 ? 0.0f : (bp5 ? b1.y : b1.x);
                v1 = bm1 ? b1.x : (bp5 ? 0.0f : b1.y);
                rB1 = fmaf(wxB[k], v1 - v0, v0);
            }
            accA = fmaf(t0A[k], rA0, accA);
            accA = fmaf(t1A[k], rA1, accA);
            accB = fmaf(t0B[k], rB0, accB);
            accB = fmaf(t1B[k], rB1, accB);
        }
        float* op = ob + (size_t)p * NPIX + idoff;
        __builtin_nontemporal_store(accA, op);
        __builtin_nontemporal_store(accB, op + 256);
    }
}

extern "C" void kernel_launch(void* const* d_in, const int* in_sizes, int n_in,
                              void* d_out, int out_size, void* d_ws, size_t ws_size,
                              hipStream_t stream) {
    const float* img  = (const float*)d_in[0];
    const float* zoom = (const float*)d_in[1];
    float* out = (float*)d_out;

    dim3 block(256);
    dim3 grid(IH * GROUPS);      // 4096 blocks; bid&7 == XCD, 3 planes each
    zoomblur_kernel<<<grid, block, 0, stream>>>(img, zoom, out);
}